// Round 2
// baseline (480.377 us; speedup 1.0000x reference)
//
#include <hip/hip_runtime.h>
#include <hip/hip_bf16.h>

#define N_NODES 2048
#define NB 16

typedef __attribute__((ext_vector_type(8))) short short8;
typedef __attribute__((ext_vector_type(4))) float f32x4;

static __device__ __forceinline__ float bfbits2f(short s) {
  unsigned int u = ((unsigned int)(unsigned short)s) << 16;
  float f; __builtin_memcpy(&f, &u, 4); return f;
}
static __device__ __forceinline__ short f2bfbits(float f) {
  __hip_bfloat16 h = __float2bfloat16(f);
  unsigned short us; __builtin_memcpy(&us, &h, 2); return (short)us;
}
static __device__ __forceinline__ float exp2_fast(float x) {
#if __has_builtin(__builtin_amdgcn_exp2f)
  return __builtin_amdgcn_exp2f(x);
#else
  return exp2f(x);
#endif
}

// ---------------------------------------------------------------------------
// BatchNorm over node axis for the 3 input fields -> x0 (bf16, [B][64][N]).
// Rows 3..15 are zeroed (layer-0 spread pads its 16-wide channel subtile).
// Stack order per reference: c0 = bn(e), c1 = bn(eta), c2 = bn(phi).
// ---------------------------------------------------------------------------
__global__ __launch_bounds__(256) void bn_kernel(
    const float* __restrict__ e, const float* __restrict__ phi,
    const float* __restrict__ eta, __hip_bfloat16* __restrict__ x0) {
  const int b = blockIdx.x;
  const int c = blockIdx.y;
  const int t = threadIdx.x;
  __hip_bfloat16* out = x0 + ((size_t)b * 64 + c) * N_NODES;
  if (c >= 3) {
    short8 z = {0, 0, 0, 0, 0, 0, 0, 0};
    for (int idx = t * 8; idx < N_NODES; idx += 256 * 8)
      *(short8*)&out[idx] = z;
    return;
  }
  const float* src = (c == 0 ? e : (c == 1 ? eta : phi)) + (size_t)b * N_NODES;
  float sum = 0.f, sq = 0.f;
  for (int idx = t * 4; idx < N_NODES; idx += 256 * 4) {
    float4 v = *(const float4*)&src[idx];
    sum += v.x + v.y + v.z + v.w;
    sq += v.x * v.x + v.y * v.y + v.z * v.z + v.w * v.w;
  }
  __shared__ float rs[256], rq[256];
  rs[t] = sum; rq[t] = sq;
  __syncthreads();
  for (int off = 128; off > 0; off >>= 1) {
    if (t < off) { rs[t] += rs[t + off]; rq[t] += rq[t + off]; }
    __syncthreads();
  }
  const float m = rs[0] * (1.f / N_NODES);
  const float var = fmaxf(rq[0] * (1.f / N_NODES) - m * m, 0.f);
  const float rinv = 1.f / (sqrtf(var) + 1e-5f);  // (x-m)/(std+EPS)
  for (int idx = t * 4; idx < N_NODES; idx += 256 * 4) {
    float4 v = *(const float4*)&src[idx];
    out[idx + 0] = __float2bfloat16((v.x - m) * rinv);
    out[idx + 1] = __float2bfloat16((v.y - m) * rinv);
    out[idx + 2] = __float2bfloat16((v.z - m) * rinv);
    out[idx + 3] = __float2bfloat16((v.w - m) * rinv);
  }
}

// ---------------------------------------------------------------------------
// Spread: s[b,c,i] = sum_j exp(-d2(i,j)) * x[b,c,j].
// adj is recomputed on the fly into the MFMA A-fragment (never hits memory).
// Per block: 128 output rows (8 waves x one 16-row subtile), all 16*CSUB chans.
// A-frag (16x16x32 bf16): lane holds A[lane&15][(lane>>4)*8 + e]; any k-perm
// error cancels because B uses the identical assumed k-mapping.
// phi/eta pre-scaled by sqrt(log2 e) so adj = exp2(-(dp^2+de^2)).
// ---------------------------------------------------------------------------
template <int CSUB>
__global__ __launch_bounds__(512) void spread_kernel(
    const float* __restrict__ phi, const float* __restrict__ eta,
    const __hip_bfloat16* __restrict__ x, __hip_bfloat16* __restrict__ s) {
  const int b = blockIdx.y;
  const int i0 = blockIdx.x * 128;
  const int tid = threadIdx.x;
  const int wave = tid >> 6;
  const int lane = tid & 63;

  __shared__ float phs[N_NODES];
  __shared__ float ehs[N_NODES];
  const float SC = 1.20112240872f;  // sqrt(log2(e))
  {
    const float* pb = phi + (size_t)b * N_NODES;
    const float* eb = eta + (size_t)b * N_NODES;
    for (int idx = tid; idx < N_NODES; idx += 512) {
      phs[idx] = pb[idx] * SC;
      ehs[idx] = eb[idx] * SC;
    }
  }
  __syncthreads();

  const int irow = i0 + wave * 16 + (lane & 15);
  const float pi_ = phs[irow];
  const float ei_ = ehs[irow];
  const int koff = (lane >> 4) * 8;

  f32x4 acc[CSUB];
#pragma unroll
  for (int cs = 0; cs < CSUB; ++cs) acc[cs] = (f32x4){0.f, 0.f, 0.f, 0.f};

  const short* xb = (const short*)(x + (size_t)b * 64 * N_NODES);

  for (int j0 = 0; j0 < N_NODES; j0 += 32) {
    const int jb = j0 + koff;
    float pj[8], ej[8];
    *(float4*)&pj[0] = *(const float4*)&phs[jb];
    *(float4*)&pj[4] = *(const float4*)&phs[jb + 4];
    *(float4*)&ej[0] = *(const float4*)&ehs[jb];
    *(float4*)&ej[4] = *(const float4*)&ehs[jb + 4];
    short8 afrag;
#pragma unroll
    for (int e8 = 0; e8 < 8; ++e8) {
      float dp = pi_ - pj[e8];
      float de = ei_ - ej[e8];
      float d2 = dp * dp + de * de;
      afrag[e8] = f2bfbits(exp2_fast(-d2));
    }
#pragma unroll
    for (int cs = 0; cs < CSUB; ++cs) {
      const int c = cs * 16 + (lane & 15);
      short8 bfrag = *(const short8*)&xb[(size_t)c * N_NODES + jb];
      acc[cs] = __builtin_amdgcn_mfma_f32_16x16x32_bf16(afrag, bfrag, acc[cs], 0, 0, 0);
    }
  }

  // D layout (verified): col = lane&15 (channel), row = (lane>>4)*4 + r (node)
  __hip_bfloat16* sb = s + (size_t)b * 64 * N_NODES;
#pragma unroll
  for (int cs = 0; cs < CSUB; ++cs) {
    const int c = cs * 16 + (lane & 15);
#pragma unroll
    for (int r = 0; r < 4; ++r) {
      const int i = i0 + wave * 16 + (lane >> 4) * 4 + r;
      sb[(size_t)c * N_NODES + i] = __float2bfloat16(acc[cs][r]);
    }
  }
}

// ---------------------------------------------------------------------------
// Pointwise: x_out[o,i] = relu(W[o,:CIN]·x[:,i] + W[o,CIN:]·s[:,i] + b[o])
//                         + Wr[o,:]·x[:,i] + br[o]
// thread = (i = t&63, o-quarter = t>>6); weight indices are wave-uniform
// (readfirstlane) so W/Wr/b come through scalar loads.
// ---------------------------------------------------------------------------
template <int CIN>
__global__ __launch_bounds__(256) void pointwise_kernel(
    const __hip_bfloat16* __restrict__ x, const __hip_bfloat16* __restrict__ s,
    const float* __restrict__ W, const float* __restrict__ bias,
    const float* __restrict__ Wr, const float* __restrict__ brs,
    __hip_bfloat16* __restrict__ xo) {
  const int b = blockIdx.y;
  const int i = blockIdx.x * 64 + (threadIdx.x & 63);
  const int oq = __builtin_amdgcn_readfirstlane((int)(threadIdx.x >> 6));
  const short* xb = (const short*)(x + (size_t)b * 64 * N_NODES);
  const short* sbp = (const short*)(s + (size_t)b * 64 * N_NODES);
  float accW[16], accR[16];
#pragma unroll
  for (int oo = 0; oo < 16; ++oo) { accW[oo] = 0.f; accR[oo] = 0.f; }
#pragma unroll 4
  for (int c = 0; c < CIN; ++c) {
    const float xc = bfbits2f(xb[(size_t)c * N_NODES + i]);
    const float sc = bfbits2f(sbp[(size_t)c * N_NODES + i]);
#pragma unroll
    for (int oo = 0; oo < 16; ++oo) {
      const int o = oq * 16 + oo;
      accW[oo] += W[o * 2 * CIN + c] * xc + W[o * 2 * CIN + CIN + c] * sc;
      accR[oo] += Wr[o * CIN + c] * xc;
    }
  }
  __hip_bfloat16* xob = xo + (size_t)b * 64 * N_NODES;
#pragma unroll
  for (int oo = 0; oo < 16; ++oo) {
    const int o = oq * 16 + oo;
    float v = fmaxf(accW[oo] + bias[o], 0.f) + accR[oo] + brs[o];
    xob[(size_t)o * N_NODES + i] = __float2bfloat16(v);
  }
}

// ---------------------------------------------------------------------------
// Final: out[b] = (1/N) * sum_{c,i} fcW[c]*x[c,i] + fcb
// ---------------------------------------------------------------------------
__global__ __launch_bounds__(256) void final_kernel(
    const __hip_bfloat16* __restrict__ x, const float* __restrict__ fcW,
    const float* __restrict__ fcb, float* __restrict__ out) {
  const int b = blockIdx.x;
  const short* xb = (const short*)(x + (size_t)b * 64 * N_NODES);
  float acc = 0.f;
  for (int f = threadIdx.x * 8; f < 64 * N_NODES; f += 256 * 8) {
    short8 v = *(const short8*)&xb[f];
    const float w = fcW[f >> 11];
    float ss = 0.f;
#pragma unroll
    for (int e8 = 0; e8 < 8; ++e8) ss += bfbits2f(v[e8]);
    acc += w * ss;
  }
  __shared__ float red[256];
  red[threadIdx.x] = acc;
  __syncthreads();
  for (int off = 128; off > 0; off >>= 1) {
    if ((int)threadIdx.x < off) red[threadIdx.x] += red[threadIdx.x + off];
    __syncthreads();
  }
  if (threadIdx.x == 0) out[b] = red[0] * (1.f / N_NODES) + fcb[0];
}

extern "C" void kernel_launch(void* const* d_in, const int* in_sizes, int n_in,
                              void* d_out, int out_size, void* d_ws, size_t ws_size,
                              hipStream_t stream) {
  const float* e   = (const float*)d_in[0];
  const float* phi = (const float*)d_in[1];
  const float* eta = (const float*)d_in[2];
  const float* W[4]  = {(const float*)d_in[3],  (const float*)d_in[7],
                        (const float*)d_in[11], (const float*)d_in[15]};
  const float* bb[4] = {(const float*)d_in[4],  (const float*)d_in[8],
                        (const float*)d_in[12], (const float*)d_in[16]};
  const float* Wr[4] = {(const float*)d_in[5],  (const float*)d_in[9],
                        (const float*)d_in[13], (const float*)d_in[17]};
  const float* br[4] = {(const float*)d_in[6],  (const float*)d_in[10],
                        (const float*)d_in[14], (const float*)d_in[18]};
  const float* fcW = (const float*)d_in[19];
  const float* fcb = (const float*)d_in[20];
  float* outp = (float*)d_out;

  const size_t XSZ = (size_t)NB * 64 * N_NODES;  // elements per buffer
  __hip_bfloat16* xA = (__hip_bfloat16*)d_ws;    // ws usage: 3 * 4 MB = 12 MB
  __hip_bfloat16* sB = xA + XSZ;
  __hip_bfloat16* xB = sB + XSZ;

  dim3 bn_grid(NB, 16);
  bn_kernel<<<bn_grid, 256, 0, stream>>>(e, phi, eta, xA);

  dim3 sp_grid(N_NODES / 128, NB);
  dim3 pw_grid(N_NODES / 64, NB);

  // layer 0 (CIN=3)
  spread_kernel<1><<<sp_grid, 512, 0, stream>>>(phi, eta, xA, sB);
  pointwise_kernel<3><<<pw_grid, 256, 0, stream>>>(xA, sB, W[0], bb[0], Wr[0], br[0], xB);
  // layer 1
  spread_kernel<4><<<sp_grid, 512, 0, stream>>>(phi, eta, xB, sB);
  pointwise_kernel<64><<<pw_grid, 256, 0, stream>>>(xB, sB, W[1], bb[1], Wr[1], br[1], xA);
  // layer 2
  spread_kernel<4><<<sp_grid, 512, 0, stream>>>(phi, eta, xA, sB);
  pointwise_kernel<64><<<pw_grid, 256, 0, stream>>>(xA, sB, W[2], bb[2], Wr[2], br[2], xB);
  // layer 3
  spread_kernel<4><<<sp_grid, 512, 0, stream>>>(phi, eta, xB, sB);
  pointwise_kernel<64><<<pw_grid, 256, 0, stream>>>(xB, sB, W[3], bb[3], Wr[3], br[3], xA);

  final_kernel<<<NB, 256, 0, stream>>>(xA, fcW, fcb, outp);
}

// Round 3
// 392.983 us; speedup vs baseline: 1.2224x; 1.2224x over previous
//
#include <hip/hip_runtime.h>
#include <hip/hip_bf16.h>

#define NN 2048
#define NB 16

typedef __attribute__((ext_vector_type(8))) short short8;
typedef __attribute__((ext_vector_type(4))) float f32x4;

static __device__ __forceinline__ float bfbits2f(short s) {
  unsigned int u = ((unsigned int)(unsigned short)s) << 16;
  float f; __builtin_memcpy(&f, &u, 4); return f;
}
static __device__ __forceinline__ short f2bfbits(float f) {
  __hip_bfloat16 h = __float2bfloat16(f);
  unsigned short us; __builtin_memcpy(&us, &h, 2); return (short)us;
}
static __device__ __forceinline__ float exp2_fast(float x) {
#if __has_builtin(__builtin_amdgcn_exp2f)
  return __builtin_amdgcn_exp2f(x);
#else
  return exp2f(x);
#endif
}

// ---------------------------------------------------------------------------
// BatchNorm over nodes -> x0 bf16 [B][64][NN]; channels 3..63 zeroed.
// c0 = bn(e), c1 = bn(eta), c2 = bn(phi).
// ---------------------------------------------------------------------------
__global__ __launch_bounds__(256) void bn_kernel(
    const float* __restrict__ e, const float* __restrict__ phi,
    const float* __restrict__ eta, __hip_bfloat16* __restrict__ x0) {
  const int b = blockIdx.x;
  const int c = blockIdx.y;
  const int t = threadIdx.x;
  __hip_bfloat16* out = x0 + ((size_t)b * 64 + c) * NN;
  if (c >= 3) {
    short8 z = {0, 0, 0, 0, 0, 0, 0, 0};
    for (int idx = t * 8; idx < NN; idx += 256 * 8) *(short8*)&out[idx] = z;
    return;
  }
  const float* src = (c == 0 ? e : (c == 1 ? eta : phi)) + (size_t)b * NN;
  float sum = 0.f, sq = 0.f;
  for (int idx = t * 4; idx < NN; idx += 256 * 4) {
    float4 v = *(const float4*)&src[idx];
    sum += v.x + v.y + v.z + v.w;
    sq += v.x * v.x + v.y * v.y + v.z * v.z + v.w * v.w;
  }
  __shared__ float rs[256], rq[256];
  rs[t] = sum; rq[t] = sq;
  __syncthreads();
  for (int off = 128; off > 0; off >>= 1) {
    if (t < off) { rs[t] += rs[t + off]; rq[t] += rq[t + off]; }
    __syncthreads();
  }
  const float m = rs[0] * (1.f / NN);
  const float var = fmaxf(rq[0] * (1.f / NN) - m * m, 0.f);
  const float rinv = 1.f / (sqrtf(var) + 1e-5f);
  for (int idx = t * 4; idx < NN; idx += 256 * 4) {
    float4 v = *(const float4*)&src[idx];
    out[idx + 0] = __float2bfloat16((v.x - m) * rinv);
    out[idx + 1] = __float2bfloat16((v.y - m) * rinv);
    out[idx + 2] = __float2bfloat16((v.z - m) * rinv);
    out[idx + 3] = __float2bfloat16((v.w - m) * rinv);
  }
}

// ---------------------------------------------------------------------------
// Prep: pack weights into MFMA A-fragment order, bf16 hi + bf16 lo residual.
// Per layer (24576 shorts): wcat_hi[8192], wcat_lo[8192], wr_hi[4096], wr_lo[4096].
// wcat: A[m=o][k], k<64 -> Wx (zero-pad c>=CIN), k>=64 -> Ws.
// frag order: f = ((osub*KS + ksub)*64 + lane)*8 + e, o=osub*16+(lane&15),
// k = ksub*32 + (lane>>4)*8 + e.
// ---------------------------------------------------------------------------
__global__ __launch_bounds__(256) void prep_kernel(
    const float* __restrict__ W0, const float* __restrict__ W1,
    const float* __restrict__ W2, const float* __restrict__ W3,
    const float* __restrict__ R0, const float* __restrict__ R1,
    const float* __restrict__ R2, const float* __restrict__ R3,
    short* __restrict__ blob) {
  const int layer = blockIdx.x;
  const float* W = layer == 0 ? W0 : layer == 1 ? W1 : layer == 2 ? W2 : W3;
  const float* R = layer == 0 ? R0 : layer == 1 ? R1 : layer == 2 ? R2 : R3;
  const int CIN = layer == 0 ? 3 : 64;
  short* base = blob + layer * 24576;
  for (int f = threadIdx.x; f < 8192; f += 256) {
    int e = f & 7, lane = (f >> 3) & 63, ks = (f >> 9) & 3, os = f >> 11;
    int o = os * 16 + (lane & 15);
    int k = ks * 32 + (lane >> 4) * 8 + e;
    float v = 0.f;
    if (k < 64) { if (k < CIN) v = W[o * 2 * CIN + k]; }
    else { int c = k - 64; if (c < CIN) v = W[o * 2 * CIN + CIN + c]; }
    short hi = f2bfbits(v);
    base[f] = hi;
    base[8192 + f] = f2bfbits(v - bfbits2f(hi));
  }
  for (int f = threadIdx.x; f < 4096; f += 256) {
    int e = f & 7, lane = (f >> 3) & 63, ks = (f >> 9) & 1, os = f >> 10;
    int o = os * 16 + (lane & 15);
    int k = ks * 32 + (lane >> 4) * 8 + e;
    float v = (k < CIN) ? R[o * CIN + k] : 0.f;
    short hi = f2bfbits(v);
    base[16384 + f] = hi;
    base[20480 + f] = f2bfbits(v - bfbits2f(hi));
  }
}

// ---------------------------------------------------------------------------
// Fused layer: s = adj @ x (adj rebuilt on the fly), then
// xo = relu(Wx.x + Ws.s + b) + Wr.x + br, all per 128-row block.
// 8 waves x 16 rows, CSUB=4 (64 channels). 4-deep prefetch pipeline.
// ---------------------------------------------------------------------------
struct Pf { float pj[8]; float ej[8]; short8 bf[4]; };

static __device__ __forceinline__ void pf_load(Pf& p, int jb,
    const float* phs, const float* ehs, const short* xb, int c0) {
  *(float4*)&p.pj[0] = *(const float4*)&phs[jb];
  *(float4*)&p.pj[4] = *(const float4*)&phs[jb + 4];
  *(float4*)&p.ej[0] = *(const float4*)&ehs[jb];
  *(float4*)&p.ej[4] = *(const float4*)&ehs[jb + 4];
#pragma unroll
  for (int cs = 0; cs < 4; ++cs)
    p.bf[cs] = *(const short8*)&xb[(size_t)(cs * 16 + c0) * NN + jb];
}
static __device__ __forceinline__ void pf_step(const Pf& p, float pi_, float ei_,
                                               f32x4* acc) {
  short8 af;
#pragma unroll
  for (int e = 0; e < 8; ++e) {
    float dp = pi_ - p.pj[e];
    float de = ei_ - p.ej[e];
    af[e] = f2bfbits(exp2_fast(-(dp * dp + de * de)));
  }
#pragma unroll
  for (int cs = 0; cs < 4; ++cs)
    acc[cs] = __builtin_amdgcn_mfma_f32_16x16x32_bf16(af, p.bf[cs], acc[cs], 0, 0, 0);
}

#define PITCH 136  // shorts per LDS tile row (272 B: 68 words == 4 mod 32 banks)

__global__ __launch_bounds__(512, 2) void layer_kernel(
    const float* __restrict__ phi, const float* __restrict__ eta,
    const __hip_bfloat16* __restrict__ x, const short* __restrict__ wcat,
    const short* __restrict__ wrb, const float* __restrict__ bias,
    const float* __restrict__ brs, __hip_bfloat16* __restrict__ xo) {
  const int b = blockIdx.y;
  const int i0 = blockIdx.x * 128;
  const int tid = threadIdx.x;
  const int wave = tid >> 6;
  const int lane = tid & 63;
  const int c0 = lane & 15;
  const int koff = (lane >> 4) * 8;

  // LDS: [0,8192) phs f32 | [8192,16384) ehs f32 | pad | [17408,52224) cat_t
  // out_t [64][PITCH] aliases [0,17408) (phs/ehs dead after the j-loop).
  __shared__ __align__(16) char smem[52224];
  float* phs = (float*)smem;
  float* ehs = (float*)(smem + 8192);
  short* out_t = (short*)smem;
  short* cat_t = (short*)(smem + 17408);  // [128 i][PITCH]: c<64 = x, c>=64 = s

  const float SC = 1.20112240872f;  // sqrt(log2 e): exp2(-(SC d)^2) = exp(-d^2)
  {
    const float* pb = phi + (size_t)b * NN;
    const float* eb = eta + (size_t)b * NN;
    for (int idx = tid; idx < NN; idx += 512) {
      phs[idx] = pb[idx] * SC;
      ehs[idx] = eb[idx] * SC;
    }
  }
  const short* xb = (const short*)(x + (size_t)b * 64 * NN);
  {
    // stage x tile transposed into cat_t[:, 0..63]
    const int c = tid >> 3, part = tid & 7;
    const short* xr = xb + (size_t)c * NN + i0 + part * 16;
    short8 v0 = *(const short8*)xr;
    short8 v1 = *(const short8*)(xr + 8);
#pragma unroll
    for (int q = 0; q < 8; ++q) cat_t[(part * 16 + q) * PITCH + c] = v0[q];
#pragma unroll
    for (int q = 0; q < 8; ++q) cat_t[(part * 16 + 8 + q) * PITCH + c] = v1[q];
  }
  __syncthreads();

  const int irow = i0 + wave * 16 + c0;
  const float pi_ = phs[irow];
  const float ei_ = ehs[irow];

  f32x4 acc[4];
#pragma unroll
  for (int cs = 0; cs < 4; ++cs) acc[cs] = (f32x4){0.f, 0.f, 0.f, 0.f};

  Pf P0, P1, P2, P3;
  pf_load(P0, 0 + koff, phs, ehs, xb, c0);
  pf_load(P1, 32 + koff, phs, ehs, xb, c0);
  pf_load(P2, 64 + koff, phs, ehs, xb, c0);
  pf_load(P3, 96 + koff, phs, ehs, xb, c0);
  for (int j0 = 0; j0 < NN; j0 += 128) {
    pf_step(P0, pi_, ei_, acc);
    pf_load(P0, ((j0 + 128) & (NN - 1)) + koff, phs, ehs, xb, c0);
    pf_step(P1, pi_, ei_, acc);
    pf_load(P1, ((j0 + 160) & (NN - 1)) + koff, phs, ehs, xb, c0);
    pf_step(P2, pi_, ei_, acc);
    pf_load(P2, ((j0 + 192) & (NN - 1)) + koff, phs, ehs, xb, c0);
    pf_step(P3, pi_, ei_, acc);
    pf_load(P3, ((j0 + 224) & (NN - 1)) + koff, phs, ehs, xb, c0);
  }

  // s D-frags -> cat_t[:, 64..127]  (D: col=lane&15 -> channel, row=(lane>>4)*4+r)
#pragma unroll
  for (int cs = 0; cs < 4; ++cs)
#pragma unroll
    for (int r = 0; r < 4; ++r) {
      const int il = wave * 16 + (lane >> 4) * 4 + r;
      cat_t[il * PITCH + 64 + cs * 16 + c0] = f2bfbits(acc[cs][r]);
    }
  __syncthreads();

  // epilogue: out[o][i] = relu(Wcat . cat + b) + Wr . x + br (MFMA, hi+lo weights)
  {
    const int irl = wave * 16 + c0;  // B-frag n-index = i
    short8 bf[4];
#pragma unroll
    for (int ks = 0; ks < 4; ++ks)
      bf[ks] = *(const short8*)&cat_t[irl * PITCH + ks * 32 + koff];
#pragma unroll
    for (int os = 0; os < 4; ++os) {
      f32x4 a1 = (f32x4){0.f, 0.f, 0.f, 0.f};
      f32x4 a2 = (f32x4){0.f, 0.f, 0.f, 0.f};
#pragma unroll
      for (int ks = 0; ks < 4; ++ks) {
        short8 whi = *(const short8*)&wcat[(size_t)(((os * 4 + ks) * 64) + lane) * 8];
        short8 wlo = *(const short8*)&wcat[8192 + (size_t)(((os * 4 + ks) * 64) + lane) * 8];
        a1 = __builtin_amdgcn_mfma_f32_16x16x32_bf16(whi, bf[ks], a1, 0, 0, 0);
        a1 = __builtin_amdgcn_mfma_f32_16x16x32_bf16(wlo, bf[ks], a1, 0, 0, 0);
      }
#pragma unroll
      for (int ks = 0; ks < 2; ++ks) {
        short8 rhi = *(const short8*)&wrb[(size_t)(((os * 2 + ks) * 64) + lane) * 8];
        short8 rlo = *(const short8*)&wrb[4096 + (size_t)(((os * 2 + ks) * 64) + lane) * 8];
        a2 = __builtin_amdgcn_mfma_f32_16x16x32_bf16(rhi, bf[ks], a2, 0, 0, 0);
        a2 = __builtin_amdgcn_mfma_f32_16x16x32_bf16(rlo, bf[ks], a2, 0, 0, 0);
      }
#pragma unroll
      for (int r = 0; r < 4; ++r) {
        const int o = os * 16 + (lane >> 4) * 4 + r;
        float v = fmaxf(a1[r] + bias[o], 0.f) + a2[r] + brs[o];
        out_t[o * PITCH + wave * 16 + c0] = f2bfbits(v);
      }
    }
  }
  __syncthreads();

  // coalesced out copy
  {
    const int o = tid >> 3, part = tid & 7;
    short8 v0 = *(const short8*)&out_t[o * PITCH + part * 16];
    short8 v1 = *(const short8*)&out_t[o * PITCH + part * 16 + 8];
    short* dst = (short*)xo + (size_t)b * 64 * NN + (size_t)o * NN + i0 + part * 16;
    *(short8*)dst = v0;
    *(short8*)(dst + 8) = v1;
  }
}

// ---------------------------------------------------------------------------
// Final: out[b] = (1/NN) * sum_{c,i} fcW[c]*x[c,i] + fcb
// ---------------------------------------------------------------------------
__global__ __launch_bounds__(256) void final_kernel(
    const __hip_bfloat16* __restrict__ x, const float* __restrict__ fcW,
    const float* __restrict__ fcb, float* __restrict__ out) {
  const int b = blockIdx.x;
  const short* xb = (const short*)(x + (size_t)b * 64 * NN);
  float acc = 0.f;
  for (int f = threadIdx.x * 8; f < 64 * NN; f += 256 * 8) {
    short8 v = *(const short8*)&xb[f];
    const float w = fcW[f >> 11];
    float ss = 0.f;
#pragma unroll
    for (int e8 = 0; e8 < 8; ++e8) ss += bfbits2f(v[e8]);
    acc += w * ss;
  }
  __shared__ float red[256];
  red[threadIdx.x] = acc;
  __syncthreads();
  for (int off = 128; off > 0; off >>= 1) {
    if ((int)threadIdx.x < off) red[threadIdx.x] += red[threadIdx.x + off];
    __syncthreads();
  }
  if (threadIdx.x == 0) out[b] = red[0] * (1.f / NN) + fcb[0];
}

extern "C" void kernel_launch(void* const* d_in, const int* in_sizes, int n_in,
                              void* d_out, int out_size, void* d_ws, size_t ws_size,
                              hipStream_t stream) {
  const float* e   = (const float*)d_in[0];
  const float* phi = (const float*)d_in[1];
  const float* eta = (const float*)d_in[2];
  const float* W[4]  = {(const float*)d_in[3],  (const float*)d_in[7],
                        (const float*)d_in[11], (const float*)d_in[15]};
  const float* bb[4] = {(const float*)d_in[4],  (const float*)d_in[8],
                        (const float*)d_in[12], (const float*)d_in[16]};
  const float* Wr[4] = {(const float*)d_in[5],  (const float*)d_in[9],
                        (const float*)d_in[13], (const float*)d_in[17]};
  const float* br[4] = {(const float*)d_in[6],  (const float*)d_in[10],
                        (const float*)d_in[14], (const float*)d_in[18]};
  const float* fcW = (const float*)d_in[19];
  const float* fcb = (const float*)d_in[20];
  float* outp = (float*)d_out;

  const size_t XSZ = (size_t)NB * 64 * NN;           // 2 MB elements -> 4 MB bytes
  __hip_bfloat16* xA = (__hip_bfloat16*)d_ws;        // [0, 4MB)
  __hip_bfloat16* xB = xA + XSZ;                     // [4MB, 8MB)
  short* blob = (short*)(xB + XSZ);                  // [8MB, 8MB+192KB)

  dim3 bn_grid(NB, 64);
  bn_kernel<<<bn_grid, 256, 0, stream>>>(e, phi, eta, xA);
  prep_kernel<<<4, 256, 0, stream>>>(W[0], W[1], W[2], W[3],
                                     Wr[0], Wr[1], Wr[2], Wr[3], blob);

  dim3 lgrid(NN / 128, NB);
  const __hip_bfloat16* xin = xA;
  __hip_bfloat16* xout = xB;
  for (int l = 0; l < 4; ++l) {
    const short* lb = blob + l * 24576;
    layer_kernel<<<lgrid, 512, 0, stream>>>(phi, eta, xin, lb, lb + 16384,
                                            bb[l], br[l], xout);
    const __hip_bfloat16* t = xout; xout = (__hip_bfloat16*)xin; xin = t;
  }
  // after 4 layers output is back in xA
  final_kernel<<<NB, 256, 0, stream>>>(xA, fcW, fcb, outp);
}

// Round 4
// 249.417 us; speedup vs baseline: 1.9260x; 1.5756x over previous
//
#include <hip/hip_runtime.h>
#include <hip/hip_bf16.h>

#define NN 2048
#define NB 16
#define XT_PITCH 88    // shorts per xt row: 64 data + 24 pad (176B, 44w == 12 mod 32)
#define CAT_PITCH 136  // shorts (272B, 68w == 4 mod 32)
#define RED_PITCH 132  // f32 (528B, 132w == 4 mod 32)

typedef __attribute__((ext_vector_type(8))) short short8;
typedef __attribute__((ext_vector_type(4))) float f32x4;

static __device__ __forceinline__ float bfbits2f(short s) {
  unsigned int u = ((unsigned int)(unsigned short)s) << 16;
  float f; __builtin_memcpy(&f, &u, 4); return f;
}
static __device__ __forceinline__ short f2bfbits(float f) {
  __hip_bfloat16 h = __float2bfloat16(f);
  unsigned short us; __builtin_memcpy(&us, &h, 2); return (short)us;
}
static __device__ __forceinline__ float exp2_fast(float x) {
#if __has_builtin(__builtin_amdgcn_exp2f)
  return __builtin_amdgcn_exp2f(x);
#else
  return exp2f(x);
#endif
}
// pack two f32 -> two bf16 (round-half-up) in one v_perm
static __device__ __forceinline__ unsigned pack2bf(float f0, float f1) {
  unsigned u0, u1;
  __builtin_memcpy(&u0, &f0, 4);
  __builtin_memcpy(&u1, &f1, 4);
  return __builtin_amdgcn_perm(u1 + 0x8000u, u0 + 0x8000u, 0x07060302u);
}

// ---------------------------------------------------------------------------
// BatchNorm over nodes -> x0 bf16 [B][64][NN]; channels 3..63 zeroed.
// ---------------------------------------------------------------------------
__global__ __launch_bounds__(256) void bn_kernel(
    const float* __restrict__ e, const float* __restrict__ phi,
    const float* __restrict__ eta, __hip_bfloat16* __restrict__ x0) {
  const int b = blockIdx.x;
  const int c = blockIdx.y;
  const int t = threadIdx.x;
  __hip_bfloat16* out = x0 + ((size_t)b * 64 + c) * NN;
  if (c >= 3) {
    short8 z = {0, 0, 0, 0, 0, 0, 0, 0};
    for (int idx = t * 8; idx < NN; idx += 256 * 8) *(short8*)&out[idx] = z;
    return;
  }
  const float* src = (c == 0 ? e : (c == 1 ? eta : phi)) + (size_t)b * NN;
  float sum = 0.f, sq = 0.f;
  for (int idx = t * 4; idx < NN; idx += 256 * 4) {
    float4 v = *(const float4*)&src[idx];
    sum += v.x + v.y + v.z + v.w;
    sq += v.x * v.x + v.y * v.y + v.z * v.z + v.w * v.w;
  }
  __shared__ float rs[256], rq[256];
  rs[t] = sum; rq[t] = sq;
  __syncthreads();
  for (int off = 128; off > 0; off >>= 1) {
    if (t < off) { rs[t] += rs[t + off]; rq[t] += rq[t + off]; }
    __syncthreads();
  }
  const float m = rs[0] * (1.f / NN);
  const float var = fmaxf(rq[0] * (1.f / NN) - m * m, 0.f);
  const float rinv = 1.f / (sqrtf(var) + 1e-5f);
  for (int idx = t * 4; idx < NN; idx += 256 * 4) {
    float4 v = *(const float4*)&src[idx];
    out[idx + 0] = __float2bfloat16((v.x - m) * rinv);
    out[idx + 1] = __float2bfloat16((v.y - m) * rinv);
    out[idx + 2] = __float2bfloat16((v.z - m) * rinv);
    out[idx + 3] = __float2bfloat16((v.w - m) * rinv);
  }
}

// ---------------------------------------------------------------------------
// Prep: pack weights into MFMA A-fragment order, bf16 hi + bf16 lo residual.
// ---------------------------------------------------------------------------
__global__ __launch_bounds__(256) void prep_kernel(
    const float* __restrict__ W0, const float* __restrict__ W1,
    const float* __restrict__ W2, const float* __restrict__ W3,
    const float* __restrict__ R0, const float* __restrict__ R1,
    const float* __restrict__ R2, const float* __restrict__ R3,
    short* __restrict__ blob) {
  const int layer = blockIdx.x;
  const float* W = layer == 0 ? W0 : layer == 1 ? W1 : layer == 2 ? W2 : W3;
  const float* R = layer == 0 ? R0 : layer == 1 ? R1 : layer == 2 ? R2 : R3;
  const int CIN = layer == 0 ? 3 : 64;
  short* base = blob + layer * 24576;
  for (int f = threadIdx.x; f < 8192; f += 256) {
    int e = f & 7, lane = (f >> 3) & 63, ks = (f >> 9) & 3, os = f >> 11;
    int o = os * 16 + (lane & 15);
    int k = ks * 32 + (lane >> 4) * 8 + e;
    float v = 0.f;
    if (k < 64) { if (k < CIN) v = W[o * 2 * CIN + k]; }
    else { int c = k - 64; if (c < CIN) v = W[o * 2 * CIN + CIN + c]; }
    short hi = f2bfbits(v);
    base[f] = hi;
    base[8192 + f] = f2bfbits(v - bfbits2f(hi));
  }
  for (int f = threadIdx.x; f < 4096; f += 256) {
    int e = f & 7, lane = (f >> 3) & 63, ks = (f >> 9) & 1, os = f >> 10;
    int o = os * 16 + (lane & 15);
    int k = ks * 32 + (lane >> 4) * 8 + e;
    float v = (k < CIN) ? R[o * CIN + k] : 0.f;
    short hi = f2bfbits(v);
    base[16384 + f] = hi;
    base[20480 + f] = f2bfbits(v - bfbits2f(hi));
  }
}

// ---------------------------------------------------------------------------
// Fused layer. Block = 128 i-rows x 64 ch. 8 waves: wave w -> row-quarter
// qw=w&3 (32 rows, 2 MFMA row-tiles), j-half h=w>>2 (1024 j each).
// x[64ch][64j] chunks double-buffered in LDS (bulk-staged, 1 barrier/interval).
// Cross-half f32 reduction in LDS, then fused pointwise epilogue (MFMA).
// ---------------------------------------------------------------------------
__global__ __launch_bounds__(512, 2) void layer_kernel(
    const float* __restrict__ phi, const float* __restrict__ eta,
    const __hip_bfloat16* __restrict__ x, const short* __restrict__ wcat,
    const short* __restrict__ wrb, const float* __restrict__ bias,
    const float* __restrict__ brs, __hip_bfloat16* __restrict__ xo) {
  const int b = blockIdx.y;
  const int i0 = blockIdx.x * 128;
  const int tid = threadIdx.x;
  const int wave = tid >> 6;
  const int lane = tid & 63;
  const int c0 = lane & 15;
  const int hh = lane >> 4;      // k-subgroup 0..3
  const int koff = hh * 8;
  const int qw = wave & 3;       // row quarter
  const int h = wave >> 2;       // j-half
  const int tl = tid & 255;      // thread index within half

  // LDS: region0 [0,17408): phs f32[2048] | ehs f32[2048]; out_t aliases after.
  //      region1 [17408,62464): xt 4 x [64][XT_PITCH] shorts (11264B each);
  //                             red f32[64][RED_PITCH] / cat [128][CAT_PITCH]
  //                             alias xt after the j-loop (barrier-ordered).
  __shared__ __align__(16) char smem[62464];
  float* phs = (float*)smem;
  float* ehs = (float*)(smem + 8192);
  short* out_t = (short*)smem;
  short* xt_base = (short*)(smem + 17408);
  float* red = (float*)(smem + 17408);
  short* cat = (short*)(smem + 17408);

  const float SC = 1.20112240872f;  // sqrt(log2 e)
  {
    const float* pb = phi + (size_t)b * NN;
    const float* eb = eta + (size_t)b * NN;
    for (int idx = tid; idx < NN; idx += 512) {
      phs[idx] = pb[idx] * SC;
      ehs[idx] = eb[idx] * SC;
    }
  }
  const short* xb = (const short*)(x + (size_t)b * 64 * NN);
  // stage chunk 0 of this half into buffer (h,0)
  {
    const int c = tl >> 2, q = tl & 3;
    const short* g = xb + (size_t)c * NN + h * 1024 + q * 16;
    short8 s0 = *(const short8*)g;
    short8 s1 = *(const short8*)(g + 8);
    short* d = xt_base + (h * 2 + 0) * (64 * XT_PITCH) + c * XT_PITCH + q * 16;
    *(short8*)d = s0;
    *(short8*)(d + 8) = s1;
  }
  __syncthreads();

  const float pi0 = phs[i0 + qw * 32 + c0];
  const float ei0 = ehs[i0 + qw * 32 + c0];
  const float pi1 = phs[i0 + qw * 32 + 16 + c0];
  const float ei1 = ehs[i0 + qw * 32 + 16 + c0];

  f32x4 acc0[4], acc1[4];
#pragma unroll
  for (int cs = 0; cs < 4; ++cs) {
    acc0[cs] = (f32x4){0.f, 0.f, 0.f, 0.f};
    acc1[cs] = (f32x4){0.f, 0.f, 0.f, 0.f};
  }

#pragma unroll 1
  for (int t = 0; t < 16; ++t) {
    // issue next-chunk staging loads early (completed & written at interval end)
    short8 ng0, ng1;
    short* nd = nullptr;
    if (t < 15) {
      const int c = tl >> 2, q = tl & 3;
      const short* g = xb + (size_t)c * NN + h * 1024 + (t + 1) * 64 + q * 16;
      ng0 = *(const short8*)g;
      ng1 = *(const short8*)(g + 8);
      nd = xt_base + (h * 2 + ((t + 1) & 1)) * (64 * XT_PITCH) + c * XT_PITCH + q * 16;
    }
    const short* xcur = xt_base + (h * 2 + (t & 1)) * (64 * XT_PITCH);
#pragma unroll
    for (int kk = 0; kk < 2; ++kk) {
      const int jb = h * 1024 + t * 64 + kk * 32 + koff;
      float pj[8], ej[8];
      *(float4*)&pj[0] = *(const float4*)&phs[jb];
      *(float4*)&pj[4] = *(const float4*)&phs[jb + 4];
      *(float4*)&ej[0] = *(const float4*)&ehs[jb];
      *(float4*)&ej[4] = *(const float4*)&ehs[jb + 4];
      unsigned au0[4], au1[4];
#pragma unroll
      for (int p = 0; p < 4; ++p) {
        float dpa = pi0 - pj[2 * p],     dea = ei0 - ej[2 * p];
        float dpb = pi0 - pj[2 * p + 1], deb = ei0 - ej[2 * p + 1];
        float fa = exp2_fast(-(dpa * dpa + dea * dea));
        float fb = exp2_fast(-(dpb * dpb + deb * deb));
        au0[p] = pack2bf(fa, fb);
        float dpc = pi1 - pj[2 * p],     dec = ei1 - ej[2 * p];
        float dpd = pi1 - pj[2 * p + 1], ded = ei1 - ej[2 * p + 1];
        float fc = exp2_fast(-(dpc * dpc + dec * dec));
        float fd = exp2_fast(-(dpd * dpd + ded * ded));
        au1[p] = pack2bf(fc, fd);
      }
      short8 af0, af1;
      __builtin_memcpy(&af0, au0, 16);
      __builtin_memcpy(&af1, au1, 16);
      const short* xk = xcur + kk * 32 + koff;
#pragma unroll
      for (int cs = 0; cs < 4; ++cs) {
        short8 bf = *(const short8*)&xk[(cs * 16 + c0) * XT_PITCH];
        acc0[cs] = __builtin_amdgcn_mfma_f32_16x16x32_bf16(af0, bf, acc0[cs], 0, 0, 0);
        acc1[cs] = __builtin_amdgcn_mfma_f32_16x16x32_bf16(af1, bf, acc1[cs], 0, 0, 0);
      }
    }
    if (t < 15) {
      *(short8*)nd = ng0;
      *(short8*)(nd + 8) = ng1;
    }
    __syncthreads();
  }

  // cross-half reduction: waves 4-7 write partial s (f32), waves 0-3 add.
  if (h == 1) {
#pragma unroll
    for (int cs = 0; cs < 4; ++cs) {
      const int c = cs * 16 + c0;
      *(f32x4*)&red[c * RED_PITCH + qw * 32 + hh * 4] = acc0[cs];
      *(f32x4*)&red[c * RED_PITCH + qw * 32 + 16 + hh * 4] = acc1[cs];
    }
  }
  __syncthreads();
  if (h == 0) {
#pragma unroll
    for (int cs = 0; cs < 4; ++cs) {
      const int c = cs * 16 + c0;
      f32x4 r0 = *(const f32x4*)&red[c * RED_PITCH + qw * 32 + hh * 4];
      f32x4 r1 = *(const f32x4*)&red[c * RED_PITCH + qw * 32 + 16 + hh * 4];
      acc0[cs] += r0;
      acc1[cs] += r1;
    }
  }
  __syncthreads();  // red dead; cat region may now be written

  // build cat tile: cols 0..63 = x (restaged from global/L2), 64..127 = s
  if (h == 0) {
#pragma unroll
    for (int cs = 0; cs < 4; ++cs)
#pragma unroll
      for (int r = 0; r < 4; ++r) {
        const int row0 = qw * 32 + hh * 4 + r;
        cat[row0 * CAT_PITCH + 64 + cs * 16 + c0] = f2bfbits(acc0[cs][r]);
        cat[(row0 + 16) * CAT_PITCH + 64 + cs * 16 + c0] = f2bfbits(acc1[cs][r]);
      }
  }
  {
    const int c = tid >> 3, part = tid & 7;
    const short* xr = xb + (size_t)c * NN + i0 + part * 16;
    short8 v0 = *(const short8*)xr;
    short8 v1 = *(const short8*)(xr + 8);
#pragma unroll
    for (int q = 0; q < 8; ++q) cat[(part * 16 + q) * CAT_PITCH + c] = v0[q];
#pragma unroll
    for (int q = 0; q < 8; ++q) cat[(part * 16 + 8 + q) * CAT_PITCH + c] = v1[q];
  }
  __syncthreads();

  // epilogue: out[o][i] = relu(Wcat . cat + b) + Wr . x + br (hi+lo weights)
  {
    const int irl = wave * 16 + c0;  // B-frag n-index = node i
    short8 bf[4];
#pragma unroll
    for (int ks = 0; ks < 4; ++ks)
      bf[ks] = *(const short8*)&cat[irl * CAT_PITCH + ks * 32 + koff];
#pragma unroll
    for (int os = 0; os < 4; ++os) {
      f32x4 a1 = (f32x4){0.f, 0.f, 0.f, 0.f};
      f32x4 a2 = (f32x4){0.f, 0.f, 0.f, 0.f};
#pragma unroll
      for (int ks = 0; ks < 4; ++ks) {
        short8 whi = *(const short8*)&wcat[(size_t)(((os * 4 + ks) * 64) + lane) * 8];
        short8 wlo = *(const short8*)&wcat[8192 + (size_t)(((os * 4 + ks) * 64) + lane) * 8];
        a1 = __builtin_amdgcn_mfma_f32_16x16x32_bf16(whi, bf[ks], a1, 0, 0, 0);
        a1 = __builtin_amdgcn_mfma_f32_16x16x32_bf16(wlo, bf[ks], a1, 0, 0, 0);
      }
#pragma unroll
      for (int ks = 0; ks < 2; ++ks) {
        short8 rhi = *(const short8*)&wrb[(size_t)(((os * 2 + ks) * 64) + lane) * 8];
        short8 rlo = *(const short8*)&wrb[4096 + (size_t)(((os * 2 + ks) * 64) + lane) * 8];
        a2 = __builtin_amdgcn_mfma_f32_16x16x32_bf16(rhi, bf[ks], a2, 0, 0, 0);
        a2 = __builtin_amdgcn_mfma_f32_16x16x32_bf16(rlo, bf[ks], a2, 0, 0, 0);
      }
#pragma unroll
      for (int r = 0; r < 4; ++r) {
        const int o = os * 16 + hh * 4 + r;
        float v = fmaxf(a1[r] + bias[o], 0.f) + a2[r] + brs[o];
        out_t[o * CAT_PITCH + wave * 16 + c0] = f2bfbits(v);
      }
    }
  }
  __syncthreads();

  // coalesced out copy
  {
    const int o = tid >> 3, part = tid & 7;
    short8 v0 = *(const short8*)&out_t[o * CAT_PITCH + part * 16];
    short8 v1 = *(const short8*)&out_t[o * CAT_PITCH + part * 16 + 8];
    short* dst = (short*)xo + (size_t)b * 64 * NN + (size_t)o * NN + i0 + part * 16;
    *(short8*)dst = v0;
    *(short8*)(dst + 8) = v1;
  }
}

// ---------------------------------------------------------------------------
// Final: out[b] = (1/NN) * sum_{c,i} fcW[c]*x[c,i] + fcb
// ---------------------------------------------------------------------------
__global__ __launch_bounds__(256) void final_kernel(
    const __hip_bfloat16* __restrict__ x, const float* __restrict__ fcW,
    const float* __restrict__ fcb, float* __restrict__ out) {
  const int b = blockIdx.x;
  const short* xb = (const short*)(x + (size_t)b * 64 * NN);
  float acc = 0.f;
  for (int f = threadIdx.x * 8; f < 64 * NN; f += 256 * 8) {
    short8 v = *(const short8*)&xb[f];
    const float w = fcW[f >> 11];
    float ss = 0.f;
#pragma unroll
    for (int e8 = 0; e8 < 8; ++e8) ss += bfbits2f(v[e8]);
    acc += w * ss;
  }
  __shared__ float red[256];
  red[threadIdx.x] = acc;
  __syncthreads();
  for (int off = 128; off > 0; off >>= 1) {
    if ((int)threadIdx.x < off) red[threadIdx.x] += red[threadIdx.x + off];
    __syncthreads();
  }
  if (threadIdx.x == 0) out[b] = red[0] * (1.f / NN) + fcb[0];
}

extern "C" void kernel_launch(void* const* d_in, const int* in_sizes, int n_in,
                              void* d_out, int out_size, void* d_ws, size_t ws_size,
                              hipStream_t stream) {
  const float* e   = (const float*)d_in[0];
  const float* phi = (const float*)d_in[1];
  const float* eta = (const float*)d_in[2];
  const float* W[4]  = {(const float*)d_in[3],  (const float*)d_in[7],
                        (const float*)d_in[11], (const float*)d_in[15]};
  const float* bb[4] = {(const float*)d_in[4],  (const float*)d_in[8],
                        (const float*)d_in[12], (const float*)d_in[16]};
  const float* Wr[4] = {(const float*)d_in[5],  (const float*)d_in[9],
                        (const float*)d_in[13], (const float*)d_in[17]};
  const float* br[4] = {(const float*)d_in[6],  (const float*)d_in[10],
                        (const float*)d_in[14], (const float*)d_in[18]};
  const float* fcW = (const float*)d_in[19];
  const float* fcb = (const float*)d_in[20];
  float* outp = (float*)d_out;

  const size_t XSZ = (size_t)NB * 64 * NN;
  __hip_bfloat16* xA = (__hip_bfloat16*)d_ws;  // [0, 4MB)
  __hip_bfloat16* xB = xA + XSZ;               // [4MB, 8MB)
  short* blob = (short*)(xB + XSZ);            // [8MB, 8MB+192KB)

  dim3 bn_grid(NB, 64);
  bn_kernel<<<bn_grid, 256, 0, stream>>>(e, phi, eta, xA);
  prep_kernel<<<4, 256, 0, stream>>>(W[0], W[1], W[2], W[3],
                                     Wr[0], Wr[1], Wr[2], Wr[3], blob);

  dim3 lgrid(NN / 128, NB);
  const __hip_bfloat16* xin = xA;
  __hip_bfloat16* xout = xB;
  for (int l = 0; l < 4; ++l) {
    const short* lb = blob + l * 24576;
    layer_kernel<<<lgrid, 512, 0, stream>>>(phi, eta, xin, lb, lb + 16384,
                                            bb[l], br[l], xout);
    const __hip_bfloat16* t = xout; xout = (__hip_bfloat16*)xin; xin = t;
  }
  final_kernel<<<NB, 256, 0, stream>>>(xA, fcW, fcb, outp);
}

// Round 5
// 247.251 us; speedup vs baseline: 1.9429x; 1.0088x over previous
//
#include <hip/hip_runtime.h>
#include <hip/hip_bf16.h>

#define NN 2048
#define NB 16
#define CAT_PITCH 136    // shorts per cat/out row (272 B == 68 words == 4 mod 32)
#define RSLOT_PITCH 68   // f32 per channel row in reduction slot (272 B)
#define XT_OFF 16384     // byte offset of swizzled x chunk buffers in smem
#define SMEM_BYTES 147456

typedef __attribute__((ext_vector_type(8))) short short8;
typedef __attribute__((ext_vector_type(4))) float f32x4;

static __device__ __forceinline__ float bfbits2f(short s) {
  unsigned int u = ((unsigned int)(unsigned short)s) << 16;
  float f; __builtin_memcpy(&f, &u, 4); return f;
}
static __device__ __forceinline__ short f2bfbits(float f) {
  __hip_bfloat16 h = __float2bfloat16(f);
  unsigned short us; __builtin_memcpy(&us, &h, 2); return (short)us;
}
static __device__ __forceinline__ float exp2_fast(float x) {
#if __has_builtin(__builtin_amdgcn_exp2f)
  return __builtin_amdgcn_exp2f(x);
#else
  return exp2f(x);
#endif
}
// pack two f32 -> two bf16 (round-half-up) in one v_perm
static __device__ __forceinline__ unsigned pack2bf(float f0, float f1) {
  unsigned u0, u1;
  __builtin_memcpy(&u0, &f0, 4);
  __builtin_memcpy(&u1, &f1, 4);
  return __builtin_amdgcn_perm(u1 + 0x8000u, u0 + 0x8000u, 0x07060302u);
}

// async global->LDS, 16B per lane, wave-uniform LDS base + lane*16
static __device__ __forceinline__ void gload_lds16(const void* g, void* l) {
  __builtin_amdgcn_global_load_lds(
      (const __attribute__((address_space(1))) unsigned int*)g,
      (__attribute__((address_space(3))) unsigned int*)l, 16, 0, 0);
}

// ---------------------------------------------------------------------------
// BatchNorm over nodes -> x0 bf16 [B][64][NN]; channels 3..63 zeroed.
// c0 = bn(e), c1 = bn(eta), c2 = bn(phi).
// ---------------------------------------------------------------------------
__global__ __launch_bounds__(256) void bn_kernel(
    const float* __restrict__ e, const float* __restrict__ phi,
    const float* __restrict__ eta, __hip_bfloat16* __restrict__ x0) {
  const int b = blockIdx.x;
  const int c = blockIdx.y;
  const int t = threadIdx.x;
  __hip_bfloat16* out = x0 + ((size_t)b * 64 + c) * NN;
  if (c >= 3) {
    short8 z = {0, 0, 0, 0, 0, 0, 0, 0};
    for (int idx = t * 8; idx < NN; idx += 256 * 8) *(short8*)&out[idx] = z;
    return;
  }
  const float* src = (c == 0 ? e : (c == 1 ? eta : phi)) + (size_t)b * NN;
  float sum = 0.f, sq = 0.f;
  for (int idx = t * 4; idx < NN; idx += 256 * 4) {
    float4 v = *(const float4*)&src[idx];
    sum += v.x + v.y + v.z + v.w;
    sq += v.x * v.x + v.y * v.y + v.z * v.z + v.w * v.w;
  }
  __shared__ float rs[256], rq[256];
  rs[t] = sum; rq[t] = sq;
  __syncthreads();
  for (int off = 128; off > 0; off >>= 1) {
    if (t < off) { rs[t] += rs[t + off]; rq[t] += rq[t + off]; }
    __syncthreads();
  }
  const float m = rs[0] * (1.f / NN);
  const float var = fmaxf(rq[0] * (1.f / NN) - m * m, 0.f);
  const float rinv = 1.f / (sqrtf(var) + 1e-5f);
  for (int idx = t * 4; idx < NN; idx += 256 * 4) {
    float4 v = *(const float4*)&src[idx];
    out[idx + 0] = __float2bfloat16((v.x - m) * rinv);
    out[idx + 1] = __float2bfloat16((v.y - m) * rinv);
    out[idx + 2] = __float2bfloat16((v.z - m) * rinv);
    out[idx + 3] = __float2bfloat16((v.w - m) * rinv);
  }
}

// ---------------------------------------------------------------------------
// Prep: pack weights into MFMA A-fragment order, bf16 hi + bf16 lo residual.
// ---------------------------------------------------------------------------
__global__ __launch_bounds__(256) void prep_kernel(
    const float* __restrict__ W0, const float* __restrict__ W1,
    const float* __restrict__ W2, const float* __restrict__ W3,
    const float* __restrict__ R0, const float* __restrict__ R1,
    const float* __restrict__ R2, const float* __restrict__ R3,
    short* __restrict__ blob) {
  const int layer = blockIdx.x;
  const float* W = layer == 0 ? W0 : layer == 1 ? W1 : layer == 2 ? W2 : W3;
  const float* R = layer == 0 ? R0 : layer == 1 ? R1 : layer == 2 ? R2 : R3;
  const int CIN = layer == 0 ? 3 : 64;
  short* base = blob + layer * 24576;
  for (int f = threadIdx.x; f < 8192; f += 256) {
    int e = f & 7, lane = (f >> 3) & 63, ks = (f >> 9) & 3, os = f >> 11;
    int o = os * 16 + (lane & 15);
    int k = ks * 32 + (lane >> 4) * 8 + e;
    float v = 0.f;
    if (k < 64) { if (k < CIN) v = W[o * 2 * CIN + k]; }
    else { int c = k - 64; if (c < CIN) v = W[o * 2 * CIN + CIN + c]; }
    short hi = f2bfbits(v);
    base[f] = hi;
    base[8192 + f] = f2bfbits(v - bfbits2f(hi));
  }
  for (int f = threadIdx.x; f < 4096; f += 256) {
    int e = f & 7, lane = (f >> 3) & 63, ks = (f >> 9) & 1, os = f >> 10;
    int o = os * 16 + (lane & 15);
    int k = ks * 32 + (lane >> 4) * 8 + e;
    float v = (k < CIN) ? R[o * CIN + k] : 0.f;
    short hi = f2bfbits(v);
    base[16384 + f] = hi;
    base[20480 + f] = f2bfbits(v - bfbits2f(hi));
  }
}

// ---------------------------------------------------------------------------
// Stage one 64-j chunk for all 8 j-groups via global_load_lds with
// pre-swizzled global source (LDS dest linear, swizzle folded into src).
// Buf layout (8 KB per (jg,parity)): granule g -> ch = g>>3 within 8-ch span,
// swizzled so byte (ch*128 + jc*2)^((ch&7)<<4) holds x[ch][jc].
// ---------------------------------------------------------------------------
static __device__ __forceinline__ void stage_chunk(
    const short* __restrict__ xb, char* smem, int wave, int lane, int tt) {
  const int par = tt & 1;
#pragma unroll
  for (int q = 0; q < 4; ++q) {
    const int s = wave * 4 + q;   // span 0..63 (1 KB each)
    const int jgs = s >> 3;       // j-group
    const int sl = s & 7;         // 8-ch span within buf
    const int ch = sl * 8 + (lane >> 3);
    const int jc8 = (lane & 7) ^ (ch & 7);
    const short* g = xb + (size_t)ch * NN + jgs * 256 + tt * 64 + jc8 * 8;
    char* l = smem + XT_OFF + jgs * 16384 + par * 8192 + sl * 1024;  // uniform
    gload_lds16(g, l);
  }
}

// ---------------------------------------------------------------------------
// Fused layer. Block = 128 i-rows x 64 ch out, 1024 threads (16 waves).
// Wave (rh = w&1, jg = w>>1): rows rh*64..+64 (4 row-tiles), j in
// [jg*256, jg*256+256) as 4 double-buffered 64-j chunks. adj rebuilt on the
// fly into A-frags; x chunks in swizzled LDS; J=8 partials merged by a
// 2-step f32 LDS tree; fused pointwise epilogue via MFMA (hi+lo weights).
// ---------------------------------------------------------------------------
__global__ __launch_bounds__(1024, 4) void layer_kernel(
    const float* __restrict__ phi, const float* __restrict__ eta,
    const __hip_bfloat16* __restrict__ x, const short* __restrict__ wcat,
    const short* __restrict__ wrb, const float* __restrict__ bias,
    const float* __restrict__ brs, __hip_bfloat16* __restrict__ xo) {
  const int b = blockIdx.y;
  const int i0 = blockIdx.x * 128;
  const int tid = threadIdx.x;
  const int wave = tid >> 6;
  const int lane = tid & 63;
  const int c0 = lane & 15;
  const int hh = lane >> 4;
  const int koff = hh * 8;
  const int rh = wave & 1;
  const int jg = wave >> 1;

  __shared__ __align__(16) char smem[SMEM_BYTES];
  float* phs = (float*)smem;            // [2048]
  float* ehs = phs + NN;                // [2048]

  const float SC = 1.20112240872f;  // sqrt(log2 e): exp2(-(SC*d)^2) = exp(-d^2)
  {
    const float* pb = phi + (size_t)b * NN;
    const float* eb = eta + (size_t)b * NN;
    for (int idx = tid; idx < NN; idx += 1024) {
      phs[idx] = pb[idx] * SC;
      ehs[idx] = eb[idx] * SC;
    }
  }
  const short* xb = (const short*)(x + (size_t)b * 64 * NN);
  stage_chunk(xb, smem, wave, lane, 0);
  __syncthreads();

  float pi_[4], ei_[4];
#pragma unroll
  for (int mt = 0; mt < 4; ++mt) {
    const int row = i0 + rh * 64 + mt * 16 + c0;
    pi_[mt] = phs[row];
    ei_[mt] = ehs[row];
  }

  f32x4 acc[4][4];
#pragma unroll
  for (int mt = 0; mt < 4; ++mt)
#pragma unroll
    for (int cs = 0; cs < 4; ++cs) acc[mt][cs] = (f32x4){0.f, 0.f, 0.f, 0.f};

  for (int t = 0; t < 4; ++t) {
    if (t < 3) stage_chunk(xb, smem, wave, lane, t + 1);
    const char* xbuf = smem + XT_OFF + jg * 16384 + (t & 1) * 8192;
    const int jbase = jg * 256 + t * 64;
#pragma unroll
    for (int kk = 0; kk < 2; ++kk) {
      const int jb = jbase + kk * 32 + koff;
      float pj[8], ej[8];
      *(float4*)&pj[0] = *(const float4*)&phs[jb];
      *(float4*)&pj[4] = *(const float4*)&phs[jb + 4];
      *(float4*)&ej[0] = *(const float4*)&ehs[jb];
      *(float4*)&ej[4] = *(const float4*)&ehs[jb + 4];
      short8 af[4];
#pragma unroll
      for (int mt = 0; mt < 4; ++mt) {
        unsigned au[4];
#pragma unroll
        for (int p = 0; p < 4; ++p) {
          float dpa = pi_[mt] - pj[2 * p],     dea = ei_[mt] - ej[2 * p];
          float dpb = pi_[mt] - pj[2 * p + 1], deb = ei_[mt] - ej[2 * p + 1];
          float fa = exp2_fast(-(dpa * dpa + dea * dea));
          float fb = exp2_fast(-(dpb * dpb + deb * deb));
          au[p] = pack2bf(fa, fb);
        }
        __builtin_memcpy(&af[mt], au, 16);
      }
      const int jc = kk * 32 + koff;
#pragma unroll
      for (int cs = 0; cs < 4; ++cs) {
        const int ch = cs * 16 + c0;
        const int boff = (ch * 128 + jc * 2) ^ ((ch & 7) << 4);
        short8 bf = *(const short8*)(xbuf + boff);
#pragma unroll
        for (int mt = 0; mt < 4; ++mt)
          acc[mt][cs] = __builtin_amdgcn_mfma_f32_16x16x32_bf16(af[mt], bf,
                                                               acc[mt][cs], 0, 0, 0);
      }
    }
    __syncthreads();
  }

  // ---- 2-step J=8 reduction tree (f32, LDS slots over dead phs/xt) ----
  float* red = (float*)smem;  // 8 slots x [64 ch][RSLOT_PITCH]
  const int slot_sz = 64 * RSLOT_PITCH;
  if (jg >= 4) {
    float* sp = red + ((jg - 4) * 2 + rh) * slot_sz;
#pragma unroll
    for (int mt = 0; mt < 4; ++mt)
#pragma unroll
      for (int cs = 0; cs < 4; ++cs)
        *(f32x4*)&sp[(cs * 16 + c0) * RSLOT_PITCH + mt * 16 + hh * 4] = acc[mt][cs];
  }
  __syncthreads();
  if (jg < 4) {
    const float* sp = red + (jg * 2 + rh) * slot_sz;
#pragma unroll
    for (int mt = 0; mt < 4; ++mt)
#pragma unroll
      for (int cs = 0; cs < 4; ++cs)
        acc[mt][cs] += *(const f32x4*)&sp[(cs * 16 + c0) * RSLOT_PITCH + mt * 16 + hh * 4];
  }
  __syncthreads();
  if (jg >= 1 && jg < 4) {
    float* sp = red + ((jg - 1) * 2 + rh) * slot_sz;
#pragma unroll
    for (int mt = 0; mt < 4; ++mt)
#pragma unroll
      for (int cs = 0; cs < 4; ++cs)
        *(f32x4*)&sp[(cs * 16 + c0) * RSLOT_PITCH + mt * 16 + hh * 4] = acc[mt][cs];
  }
  __syncthreads();
  if (jg == 0) {
#pragma unroll
    for (int k = 0; k < 3; ++k) {
      const float* sp = red + (k * 2 + rh) * slot_sz;
#pragma unroll
      for (int mt = 0; mt < 4; ++mt)
#pragma unroll
        for (int cs = 0; cs < 4; ++cs)
          acc[mt][cs] += *(const f32x4*)&sp[(cs * 16 + c0) * RSLOT_PITCH + mt * 16 + hh * 4];
    }
  }
  __syncthreads();  // slots dead; cat/out region may be written

  // ---- build cat tile: cols 0..63 = x (from L2), 64..127 = s ----
  short* cat = (short*)smem;                          // [128][CAT_PITCH]
  short* out_t = (short*)(smem + 128 * CAT_PITCH * 2);  // [64][CAT_PITCH]
  if (jg == 0) {
#pragma unroll
    for (int mt = 0; mt < 4; ++mt)
#pragma unroll
      for (int cs = 0; cs < 4; ++cs)
#pragma unroll
        for (int r = 0; r < 4; ++r) {
          const int irow = rh * 64 + mt * 16 + hh * 4 + r;  // D: row=(lane>>4)*4+r
          cat[irow * CAT_PITCH + 64 + cs * 16 + c0] = f2bfbits(acc[mt][cs][r]);
        }
  }
  {
    const int c = tid & 63, rp = tid >> 6;
    short8 v = *(const short8*)&xb[(size_t)c * NN + i0 + rp * 8];
#pragma unroll
    for (int q = 0; q < 8; ++q) cat[(rp * 8 + q) * CAT_PITCH + c] = v[q];
  }
  __syncthreads();

  // ---- epilogue: out[o][i] = relu(Wcat.cat + b) + Wr.x + br ----
  {
    const int it = wave & 7;   // i-tile (16 rows)
    const int oh = wave >> 3;  // o-half (32 outputs)
    const int irl = it * 16 + c0;
    short8 bfx[4];
#pragma unroll
    for (int ks = 0; ks < 4; ++ks)
      bfx[ks] = *(const short8*)&cat[irl * CAT_PITCH + ks * 32 + koff];
#pragma unroll
    for (int osl = 0; osl < 2; ++osl) {
      const int os = oh * 2 + osl;
      f32x4 a1 = (f32x4){0.f, 0.f, 0.f, 0.f};
      f32x4 a2 = (f32x4){0.f, 0.f, 0.f, 0.f};
#pragma unroll
      for (int ks = 0; ks < 4; ++ks) {
        short8 whi = *(const short8*)&wcat[(size_t)(((os * 4 + ks) * 64) + lane) * 8];
        short8 wlo = *(const short8*)&wcat[8192 + (size_t)(((os * 4 + ks) * 64) + lane) * 8];
        a1 = __builtin_amdgcn_mfma_f32_16x16x32_bf16(whi, bfx[ks], a1, 0, 0, 0);
        a1 = __builtin_amdgcn_mfma_f32_16x16x32_bf16(wlo, bfx[ks], a1, 0, 0, 0);
      }
#pragma unroll
      for (int ks = 0; ks < 2; ++ks) {
        short8 rhi = *(const short8*)&wrb[(size_t)(((os * 2 + ks) * 64) + lane) * 8];
        short8 rlo = *(const short8*)&wrb[4096 + (size_t)(((os * 2 + ks) * 64) + lane) * 8];
        a2 = __builtin_amdgcn_mfma_f32_16x16x32_bf16(rhi, bfx[ks], a2, 0, 0, 0);
        a2 = __builtin_amdgcn_mfma_f32_16x16x32_bf16(rlo, bfx[ks], a2, 0, 0, 0);
      }
#pragma unroll
      for (int r = 0; r < 4; ++r) {
        const int o = os * 16 + hh * 4 + r;
        float v = fmaxf(a1[r] + bias[o], 0.f) + a2[r] + brs[o];
        out_t[o * CAT_PITCH + it * 16 + c0] = f2bfbits(v);
      }
    }
  }
  __syncthreads();

  // coalesced out copy
  {
    const int o = tid >> 4, part = tid & 15;
    short8 v = *(const short8*)&out_t[o * CAT_PITCH + part * 8];
    short* dst = (short*)xo + (size_t)b * 64 * NN + (size_t)o * NN + i0 + part * 8;
    *(short8*)dst = v;
  }
}

// ---------------------------------------------------------------------------
// Final: out[b] = (1/NN) * sum_{c,i} fcW[c]*x[c,i] + fcb
// ---------------------------------------------------------------------------
__global__ __launch_bounds__(256) void final_kernel(
    const __hip_bfloat16* __restrict__ x, const float* __restrict__ fcW,
    const float* __restrict__ fcb, float* __restrict__ out) {
  const int b = blockIdx.x;
  const short* xb = (const short*)(x + (size_t)b * 64 * NN);
  float acc = 0.f;
  for (int f = threadIdx.x * 8; f < 64 * NN; f += 256 * 8) {
    short8 v = *(const short8*)&xb[f];
    const float w = fcW[f >> 11];
    float ss = 0.f;
#pragma unroll
    for (int e8 = 0; e8 < 8; ++e8) ss += bfbits2f(v[e8]);
    acc += w * ss;
  }
  __shared__ float red[256];
  red[threadIdx.x] = acc;
  __syncthreads();
  for (int off = 128; off > 0; off >>= 1) {
    if ((int)threadIdx.x < off) red[threadIdx.x] += red[threadIdx.x + off];
    __syncthreads();
  }
  if (threadIdx.x == 0) out[b] = red[0] * (1.f / NN) + fcb[0];
}

extern "C" void kernel_launch(void* const* d_in, const int* in_sizes, int n_in,
                              void* d_out, int out_size, void* d_ws, size_t ws_size,
                              hipStream_t stream) {
  const float* e   = (const float*)d_in[0];
  const float* phi = (const float*)d_in[1];
  const float* eta = (const float*)d_in[2];
  const float* W[4]  = {(const float*)d_in[3],  (const float*)d_in[7],
                        (const float*)d_in[11], (const float*)d_in[15]};
  const float* bb[4] = {(const float*)d_in[4],  (const float*)d_in[8],
                        (const float*)d_in[12], (const float*)d_in[16]};
  const float* Wr[4] = {(const float*)d_in[5],  (const float*)d_in[9],
                        (const float*)d_in[13], (const float*)d_in[17]};
  const float* br[4] = {(const float*)d_in[6],  (const float*)d_in[10],
                        (const float*)d_in[14], (const float*)d_in[18]};
  const float* fcW = (const float*)d_in[19];
  const float* fcb = (const float*)d_in[20];
  float* outp = (float*)d_out;

  const size_t XSZ = (size_t)NB * 64 * NN;
  __hip_bfloat16* xA = (__hip_bfloat16*)d_ws;  // [0, 4MB)
  __hip_bfloat16* xB = xA + XSZ;               // [4MB, 8MB)
  short* blob = (short*)(xB + XSZ);            // [8MB, 8MB+192KB)

  dim3 bn_grid(NB, 64);
  bn_kernel<<<bn_grid, 256, 0, stream>>>(e, phi, eta, xA);
  prep_kernel<<<4, 256, 0, stream>>>(W[0], W[1], W[2], W[3],
                                     Wr[0], Wr[1], Wr[2], Wr[3], blob);

  dim3 lgrid(NN / 128, NB);
  const __hip_bfloat16* xin = xA;
  __hip_bfloat16* xout = xB;
  for (int l = 0; l < 4; ++l) {
    const short* lb = blob + l * 24576;
    layer_kernel<<<lgrid, 1024, 0, stream>>>(phi, eta, xin, lb, lb + 16384,
                                             bb[l], br[l], xout);
    const __hip_bfloat16* t = xout; xout = (__hip_bfloat16*)xin; xin = t;
  }
  final_kernel<<<NB, 256, 0, stream>>>(xA, fcW, fcb, outp);
}